// Round 1
// baseline (1093.479 us; speedup 1.0000x reference)
//
#include <hip/hip_runtime.h>
#include <math.h>

#define LEPS 1e-5f
static constexpr int NPOS = 65536;   // B*H*W = 16*64*64

// ---------------------------------------------------------------------------
// Generic 64x64-tile fp32 GEMM over N=65536 positions.
//   out[p][o] = epilogue( sum_k A[p][k] * Wm[o][k] )
// AMODE 0: A0 row-major with row stride ARS
// AMODE 1: A0 = x in NCHW (B=16, C=256, HW=4096): A[p][k] = x[(p>>12)*256+k][p&4095]
// AMODE 2: concat: k<256 -> A0 (y, stride 256), else A1 (f, stride 128)
// EPI 0: +bias            (qkv)
// EPI 1: BN+SiLU, NHWC out (cv1 -> y)
// EPI 2: BN+SiLU, NCHW out (cv2 -> final)
// EPI 3: +bias, exact GELU (ffn1)
// EPI 4: res(y2) + (v+bias)*gamma   (proj -> f)   q0=gamma, q1=y
// EPI 5: out += v + bias   (ffn2 residual, in place on f)
// ---------------------------------------------------------------------------
template<int KDIM, int ARS, int AMODE, int EPI>
__global__ __launch_bounds__(256)
void gemm_k(const float* __restrict__ A0, const float* __restrict__ A1,
            const float* __restrict__ Wm, const float* __restrict__ bias,
            const float* __restrict__ q0, const float* __restrict__ q1,
            const float* __restrict__ q2, const float* __restrict__ q3,
            float* __restrict__ out, int ors)
{
    __shared__ float As[64][64];   // [k][pos]
    __shared__ float Ws[64][64];   // [o][k]
    const int t   = threadIdx.x;
    const int p0i = blockIdx.x * 64;   // 64 consecutive positions = one (b,h) row
    const int o0  = blockIdx.y * 64;
    const int tp  = (t & 15) * 4;      // micro-tile position offset
    const int to  = (t >> 4) * 4;      // micro-tile channel offset
    float acc[4][4] = {};
    const int la_w = t & 63, la_k = t >> 6;

    for (int k0 = 0; k0 < KDIM; k0 += 64) {
        // stage A tile (coalesced along positions)
#pragma unroll
        for (int i = 0; i < 16; i++) {
            int kk = la_k + i * 4;
            int k  = k0 + kk;
            int p  = p0i + la_w;
            float v;
            if (AMODE == 0) {
                v = A0[(size_t)p * ARS + k];
            } else if (AMODE == 1) {
                v = A0[((size_t)((p >> 12) * 256 + k) << 12) + (p & 4095)];
            } else {
                v = (k < 256) ? A0[(size_t)p * 256 + k]
                              : A1[(size_t)p * 128 + (k - 256)];
            }
            As[kk][la_w] = v;
        }
        // stage W tile (coalesced along k); store o-major -> conflict-free
#pragma unroll
        for (int i = 0; i < 16; i++) {
            int oo = la_k + i * 4;
            Ws[oo][la_w] = Wm[(size_t)(o0 + oo) * KDIM + (k0 + la_w)];
        }
        __syncthreads();
#pragma unroll
        for (int kk = 0; kk < 64; kk++) {
            float a[4], b[4];
#pragma unroll
            for (int i = 0; i < 4; i++) a[i] = As[kk][tp + i];
#pragma unroll
            for (int j = 0; j < 4; j++) b[j] = Ws[to + j][kk];
#pragma unroll
            for (int i = 0; i < 4; i++)
#pragma unroll
                for (int j = 0; j < 4; j++) acc[i][j] += a[i] * b[j];
        }
        __syncthreads();
    }
    // epilogue
#pragma unroll
    for (int i = 0; i < 4; i++) {
        int p = p0i + tp + i;
#pragma unroll
        for (int j = 0; j < 4; j++) {
            int o = o0 + to + j;
            float v = acc[i][j];
            if (EPI == 0) {
                v += bias[o];
            } else if (EPI == 1 || EPI == 2) {
                v = (v - q2[o]) * rsqrtf(q3[o] + LEPS) * q0[o] + q1[o];
                v = v / (1.f + expf(-v));                   // SiLU
            } else if (EPI == 3) {
                v += bias[o];
                v = 0.5f * v * (1.f + erff(v * 0.70710678118654752f)); // exact GELU
            } else if (EPI == 4) {
                v = q1[(size_t)p * 256 + 128 + o] + (v + bias[o]) * q0[o];
            } else if (EPI == 5) {
                v = out[(size_t)p * (size_t)ors + o] + v + bias[o];
            }
            if (EPI == 2) {
                out[(((size_t)(p >> 12) * 256 + o) << 12) + (p & 4095)] = v;
            } else {
                out[(size_t)p * (size_t)ors + o] = v;
            }
        }
    }
}

// ---------------------------------------------------------------------------
// LayerNorm over last dim 128; one wave (64 lanes) per position.
// ---------------------------------------------------------------------------
__global__ __launch_bounds__(256)
void ln_k(const float* __restrict__ src, int rs,
          const float* __restrict__ g, const float* __restrict__ b,
          float* __restrict__ out)
{
    const int lane = threadIdx.x & 63;
    const int p = blockIdx.x * 4 + (threadIdx.x >> 6);
    const float* row = src + (size_t)p * rs;
    float v0 = row[lane], v1 = row[lane + 64];
    float s = v0 + v1, s2 = v0 * v0 + v1 * v1;
#pragma unroll
    for (int off = 32; off; off >>= 1) {
        s  += __shfl_down(s, off);
        s2 += __shfl_down(s2, off);
    }
    s = __shfl(s, 0); s2 = __shfl(s2, 0);
    float mu = s * (1.f / 128.f);
    float var = s2 * (1.f / 128.f) - mu * mu;
    float r = rsqrtf(var + LEPS);
    out[(size_t)p * 128 + lane]      = (v0 - mu) * r * g[lane]      + b[lane];
    out[(size_t)p * 128 + lane + 64] = (v1 - mu) * r * g[lane + 64] + b[lane + 64];
}

// ---------------------------------------------------------------------------
// Axial decay attention. One wave per (b, head, line).
// DIRH=1: attend along H at fixed w (writes out_h).
// DIRH=0: attend along W at fixed h (attn = 0.5*(attn + out_w)).
// qkv layout: [p][which*128 + n*16 + d], p = b*4096 + h*64 + w
// ---------------------------------------------------------------------------
template<int DIRH>
__global__ __launch_bounds__(64)
void attn_k(const float* __restrict__ qkv, float* __restrict__ attn)
{
    __shared__ float Ks[64][17];
    __shared__ float Vs[64][17];
    const int t = threadIdx.x;
    const int blk = blockIdx.x;
    const int fixed = blk & 63;          // w (DIRH) or h
    const int n = (blk >> 6) & 7;
    const int b = blk >> 9;
    const float dec = logf(1.f - exp2f(-2.f - 0.5f * (float)n));
    const int stride = DIRH ? 64 : 1;
    const int off0 = DIRH ? fixed : fixed * 64;
    const size_t base = (size_t)b * 4096 + off0;
    const size_t rowp = (base + (size_t)t * stride) * 384 + n * 16;
    float q[16];
#pragma unroll
    for (int d = 0; d < 16; d++) {
        q[d]     = qkv[rowp + d];
        Ks[t][d] = qkv[rowp + 128 + d];
        Vs[t][d] = qkv[rowp + 256 + d];
    }
    __syncthreads();
    float o[16] = {};
    for (int j = 0; j < 64; j++) {
        float s = 0.f;
#pragma unroll
        for (int d = 0; d < 16; d++) s += q[d] * Ks[j][d];
        s *= expf(dec * fabsf((float)(t - j)));
#pragma unroll
        for (int d = 0; d < 16; d++) o[d] += s * Vs[j][d];
    }
    const size_t op = (base + (size_t)t * stride) * 128 + n * 16;
    if (DIRH) {
#pragma unroll
        for (int d = 0; d < 16; d++) attn[op + d] = o[d];
    } else {
#pragma unroll
        for (int d = 0; d < 16; d++) attn[op + d] = 0.5f * (attn[op + d] + o[d]);
    }
}

// ---------------------------------------------------------------------------
extern "C" void kernel_launch(void* const* d_in, const int* in_sizes, int n_in,
                              void* d_out, int out_size, void* d_ws, size_t ws_size,
                              hipStream_t stream)
{
    const float* x      = (const float*)d_in[0];
    const float* cv1_w  = (const float*)d_in[1];
    const float* bn1_g  = (const float*)d_in[2];
    const float* bn1_b  = (const float*)d_in[3];
    const float* bn1_m  = (const float*)d_in[4];
    const float* bn1_v  = (const float*)d_in[5];
    const float* cv2_w  = (const float*)d_in[6];
    const float* bn2_g  = (const float*)d_in[7];
    const float* bn2_b  = (const float*)d_in[8];
    const float* bn2_m  = (const float*)d_in[9];
    const float* bn2_v  = (const float*)d_in[10];
    const float* ln1_g  = (const float*)d_in[11];
    const float* ln1_b  = (const float*)d_in[12];
    const float* qkv_w  = (const float*)d_in[13];
    const float* qkv_b  = (const float*)d_in[14];
    const float* proj_w = (const float*)d_in[15];
    const float* proj_b = (const float*)d_in[16];
    const float* gamma  = (const float*)d_in[17];
    const float* ln2_g  = (const float*)d_in[18];
    const float* ln2_b  = (const float*)d_in[19];
    const float* ffn_w1 = (const float*)d_in[20];
    const float* ffn_b1 = (const float*)d_in[21];
    const float* ffn_w2 = (const float*)d_in[22];
    const float* ffn_b2 = (const float*)d_in[23];

    float* ws   = (float*)d_ws;
    float* y    = ws;                        // N*256 (y1 | y2), NHWC
    float* f    = ws + (size_t)NPOS * 256;   // N*128 residual stream
    float* tmp  = ws + (size_t)NPOS * 384;   // N*128 (fn1 / attn_out / fn2)
    float* qkvb = ws + (size_t)NPOS * 512;   // N*384 (qkv, reused as h1)
    float* out  = (float*)d_out;

    // 1) cv1 + BN + SiLU -> y (NHWC)
    gemm_k<256, 0, 1, 1><<<dim3(1024, 4), 256, 0, stream>>>(
        x, nullptr, cv1_w, nullptr, bn1_g, bn1_b, bn1_m, bn1_v, y, 256);
    // 2) LN1(y2) -> tmp
    ln_k<<<dim3(16384), 256, 0, stream>>>(y + 128, 256, ln1_g, ln1_b, tmp);
    // 3) qkv = fn @ qkv_w^T + b -> qkvb
    gemm_k<128, 128, 0, 0><<<dim3(1024, 6), 256, 0, stream>>>(
        tmp, nullptr, qkv_w, qkv_b, nullptr, nullptr, nullptr, nullptr, qkvb, 384);
    // 4) axial attention -> tmp (out_h then 0.5*(out_h+out_w))
    attn_k<1><<<dim3(8192), 64, 0, stream>>>(qkvb, tmp);
    attn_k<0><<<dim3(8192), 64, 0, stream>>>(qkvb, tmp);
    // 5) f = y2 + (attn @ proj_w^T + b) * gamma
    gemm_k<128, 128, 0, 4><<<dim3(1024, 2), 256, 0, stream>>>(
        tmp, nullptr, proj_w, proj_b, gamma, y, nullptr, nullptr, f, 128);
    // 6) LN2(f) -> tmp
    ln_k<<<dim3(16384), 256, 0, stream>>>(f, 128, ln2_g, ln2_b, tmp);
    // 7) h1 = gelu(fn2 @ w1^T + b1) -> qkvb (reused)
    gemm_k<128, 128, 0, 3><<<dim3(1024, 4), 256, 0, stream>>>(
        tmp, nullptr, ffn_w1, ffn_b1, nullptr, nullptr, nullptr, nullptr, qkvb, 256);
    // 8) f += h1 @ w2^T + b2
    gemm_k<256, 256, 0, 5><<<dim3(1024, 2), 256, 0, stream>>>(
        qkvb, nullptr, ffn_w2, ffn_b2, nullptr, nullptr, nullptr, nullptr, f, 128);
    // 9) cv2(concat[y1,y2,f]) + BN + SiLU -> out (NCHW)
    gemm_k<384, 0, 2, 2><<<dim3(1024, 4), 256, 0, stream>>>(
        y, f, cv2_w, nullptr, bn2_g, bn2_b, bn2_m, bn2_v, out, 0);
}

// Round 2
// 580.082 us; speedup vs baseline: 1.8850x; 1.8850x over previous
//
#include <hip/hip_runtime.h>
#include <math.h>

#define LEPS 1e-5f
static constexpr int NPOS = 65536;   // B*H*W = 16*64*64

typedef __attribute__((ext_vector_type(8))) short short8;
typedef __attribute__((ext_vector_type(4))) float floatx4;

__device__ __forceinline__ ushort f2bf(float f) {
    unsigned int u = __float_as_uint(f);
    u += 0x7FFF + ((u >> 16) & 1);          // round-to-nearest-even
    return (ushort)(u >> 16);
}

// ---------------------------------------------------------------------------
// x NCHW fp32 -> xT [p][c] bf16  (p = b*4096 + hw)
// ---------------------------------------------------------------------------
__global__ __launch_bounds__(256)
void tr_k(const float* __restrict__ x, ushort* __restrict__ xT)
{
    __shared__ float tile[64][65];
    const int t = threadIdx.x;
    const int bi = blockIdx.x;          // 16 b * 4 ctile * 64 hwtile
    const int hwt = bi & 63, ct = (bi >> 6) & 3, b = bi >> 8;
    const int p0 = b * 4096 + hwt * 64, c0 = ct * 64;
    const float* src = x + ((size_t)(b * 256 + c0) << 12) + hwt * 64;
#pragma unroll
    for (int i = 0; i < 16; i++) {
        int cc = (t >> 6) + i * 4;
        tile[cc][t & 63] = src[((size_t)cc << 12) + (t & 63)];
    }
    __syncthreads();
#pragma unroll
    for (int i = 0; i < 16; i++) {
        int pp = (t >> 6) + i * 4;
        xT[(size_t)(p0 + pp) * 256 + c0 + (t & 63)] = f2bf(tile[t & 63][pp]);
    }
}

// ---------------------------------------------------------------------------
// MFMA bf16 GEMM, 128x128 tile, BK=64. out[p][o] = epi(sum_k A[p][k]*W[o][k])
// AMODE 0: A fp32, row stride ARS.  AMODE 1: A bf16 (xT), stride ARS.
// AMODE 2: concat fp32 (k<256 -> A0 stride 256, else A1 stride 128)
// EPI 0:+bias  1:BN+SiLU NHWC  2:BN+SiLU NCHW  3:+bias,GELU
// EPI 4: y2-res + (v+bias)*gamma   EPI 5: out += v+bias
// ---------------------------------------------------------------------------
template<int KDIM, int ARS, int AMODE, int EPI>
__global__ __launch_bounds__(256)
void gemm_k(const float* __restrict__ A0, const ushort* __restrict__ A0h,
            const float* __restrict__ A1,
            const float* __restrict__ Wm, const float* __restrict__ bias,
            const float* __restrict__ q0, const float* __restrict__ q1,
            const float* __restrict__ q2, const float* __restrict__ q3,
            float* __restrict__ out, int ors)
{
    __shared__ __align__(16) ushort As[128][80];   // [m][k], pad->40 banks
    __shared__ __align__(16) ushort Bs[128][80];   // [o][k]
    const int t = threadIdx.x;
    const int p0 = blockIdx.x * 128;
    const int o0 = blockIdx.y * 128;
    const int row = t >> 1, half = t & 1;           // staging map
    const int lane = t & 63, wv = t >> 6;
    const int wm = (wv & 1) * 64, wn = (wv >> 1) * 64;
    const int ln15 = lane & 15, quad = lane >> 4;
    floatx4 acc[4][4] = {};

    for (int k0 = 0; k0 < KDIM; k0 += 64) {
        // ---- stage A tile (128 x 64) ----
        if (AMODE == 1) {
            const ushort* s = A0h + (size_t)(p0 + row) * ARS + k0 + half * 32;
#pragma unroll
            for (int i = 0; i < 4; i++)
                *(uint4*)&As[row][half * 32 + i * 8] = ((const uint4*)s)[i];
        } else {
            const float* s;
            if (AMODE == 2) {
                if (k0 < 256) s = A0 + (size_t)(p0 + row) * 256 + k0 + half * 32;
                else          s = A1 + (size_t)(p0 + row) * 128 + (k0 - 256) + half * 32;
            } else {
                s = A0 + (size_t)(p0 + row) * ARS + k0 + half * 32;
            }
#pragma unroll
            for (int i = 0; i < 8; i++) {
                float4 v = ((const float4*)s)[i];
                ushort4 h = { f2bf(v.x), f2bf(v.y), f2bf(v.z), f2bf(v.w) };
                *(ushort4*)&As[row][half * 32 + i * 4] = h;
            }
        }
        // ---- stage W tile (128 x 64) ----
        {
            const float* s = Wm + (size_t)(o0 + row) * KDIM + k0 + half * 32;
#pragma unroll
            for (int i = 0; i < 8; i++) {
                float4 v = ((const float4*)s)[i];
                ushort4 h = { f2bf(v.x), f2bf(v.y), f2bf(v.z), f2bf(v.w) };
                *(ushort4*)&Bs[row][half * 32 + i * 4] = h;
            }
        }
        __syncthreads();
        // ---- MFMA: each wave 64x64 via 4x4 tiles of 16x16x32 ----
#pragma unroll
        for (int kc = 0; kc < 64; kc += 32) {
            short8 a[4], b[4];
#pragma unroll
            for (int i = 0; i < 4; i++)
                a[i] = *(const short8*)&As[wm + i * 16 + ln15][kc + quad * 8];
#pragma unroll
            for (int j = 0; j < 4; j++)
                b[j] = *(const short8*)&Bs[wn + j * 16 + ln15][kc + quad * 8];
#pragma unroll
            for (int i = 0; i < 4; i++)
#pragma unroll
                for (int j = 0; j < 4; j++)
                    acc[i][j] = __builtin_amdgcn_mfma_f32_16x16x32_bf16(
                        a[i], b[j], acc[i][j], 0, 0, 0);
        }
        __syncthreads();
    }
    // ---- epilogue: C row = m = quad*4+reg, col = n = ln15 ----
#pragma unroll
    for (int i = 0; i < 4; i++) {
#pragma unroll
        for (int r = 0; r < 4; r++) {
            const int p = p0 + wm + i * 16 + quad * 4 + r;
#pragma unroll
            for (int j = 0; j < 4; j++) {
                const int o = o0 + wn + j * 16 + ln15;
                float v = acc[i][j][r];
                if (EPI == 0) {
                    v += bias[o];
                } else if (EPI == 1 || EPI == 2) {
                    v = (v - q2[o]) * rsqrtf(q3[o] + LEPS) * q0[o] + q1[o];
                    v = v / (1.f + expf(-v));
                } else if (EPI == 3) {
                    v += bias[o];
                    v = 0.5f * v * (1.f + erff(v * 0.70710678118654752f));
                } else if (EPI == 4) {
                    v = q1[(size_t)p * 256 + 128 + o] + (v + bias[o]) * q0[o];
                } else if (EPI == 5) {
                    v = out[(size_t)p * (size_t)ors + o] + v + bias[o];
                }
                if (EPI == 2) {
                    out[(((size_t)(p >> 12) * 256 + o) << 12) + (p & 4095)] = v;
                } else {
                    out[(size_t)p * (size_t)ors + o] = v;
                }
            }
        }
    }
}

// ---------------------------------------------------------------------------
// LayerNorm over last dim 128; one wave per position, float2 per lane.
// ---------------------------------------------------------------------------
__global__ __launch_bounds__(256)
void ln_k(const float* __restrict__ src, int rs,
          const float* __restrict__ g, const float* __restrict__ b,
          float* __restrict__ out)
{
    const int lane = threadIdx.x & 63;
    const int p = blockIdx.x * 4 + (threadIdx.x >> 6);
    const float2 v = *(const float2*)(src + (size_t)p * rs + lane * 2);
    float s = v.x + v.y, s2 = v.x * v.x + v.y * v.y;
#pragma unroll
    for (int off = 32; off; off >>= 1) {
        s  += __shfl_down(s, off);
        s2 += __shfl_down(s2, off);
    }
    s = __shfl(s, 0); s2 = __shfl(s2, 0);
    const float mu = s * (1.f / 128.f);
    const float r = rsqrtf(s2 * (1.f / 128.f) - mu * mu + LEPS);
    const float2 gg = *(const float2*)(g + lane * 2);
    const float2 bb = *(const float2*)(b + lane * 2);
    float2 o;
    o.x = (v.x - mu) * r * gg.x + bb.x;
    o.y = (v.y - mu) * r * gg.y + bb.y;
    *(float2*)(out + (size_t)p * 128 + lane * 2) = o;
}

// ---------------------------------------------------------------------------
// Axial decay attention. 4 waves/block, one (b,head,line) per wave.
// DIRH=1 along H (writes), DIRH=0 along W (merges 0.5*(old+new)).
// ---------------------------------------------------------------------------
template<int DIRH>
__global__ __launch_bounds__(256)
void attn_k(const float* __restrict__ qkv, float* __restrict__ attn)
{
    __shared__ float4 Ks[4][64][4];
    __shared__ float4 Vs[4][64][4];
    __shared__ float dpow[64];
    const int t = threadIdx.x, wv = t >> 6, lane = t & 63;
    const int blk = blockIdx.x;               // (b*8+n)*16 + lg
    const int lg = blk & 15, n = (blk >> 4) & 7, b = blk >> 7;
    if (t < 64) {
        const float dec = logf(1.f - exp2f(-2.f - 0.5f * (float)n));
        dpow[t] = expf(dec * (float)t);
    }
    const int fixed = lg * 4 + wv;
    const int stride = DIRH ? 64 : 1;
    const size_t base = (size_t)b * 4096 + (DIRH ? fixed : fixed * 64);
    const float4* qp = (const float4*)(qkv + (base + (size_t)lane * stride) * 384 + n * 16);
    const float4 q0 = qp[0], q1 = qp[1], q2 = qp[2], q3 = qp[3];
#pragma unroll
    for (int d = 0; d < 4; d++) Ks[wv][lane][d] = qp[32 + d];
#pragma unroll
    for (int d = 0; d < 4; d++) Vs[wv][lane][d] = qp[64 + d];
    __syncthreads();
    float4 o0 = {0,0,0,0}, o1 = {0,0,0,0}, o2 = {0,0,0,0}, o3 = {0,0,0,0};
    for (int j = 0; j < 64; j++) {
        const float4 k0 = Ks[wv][j][0], k1 = Ks[wv][j][1],
                     k2 = Ks[wv][j][2], k3 = Ks[wv][j][3];
        float s = q0.x*k0.x + q0.y*k0.y + q0.z*k0.z + q0.w*k0.w
                + q1.x*k1.x + q1.y*k1.y + q1.z*k1.z + q1.w*k1.w
                + q2.x*k2.x + q2.y*k2.y + q2.z*k2.z + q2.w*k2.w
                + q3.x*k3.x + q3.y*k3.y + q3.z*k3.z + q3.w*k3.w;
        int dj = lane - j; if (dj < 0) dj = -dj;
        s *= dpow[dj];
        const float4 v0 = Vs[wv][j][0], v1 = Vs[wv][j][1],
                     v2 = Vs[wv][j][2], v3 = Vs[wv][j][3];
        o0.x += s*v0.x; o0.y += s*v0.y; o0.z += s*v0.z; o0.w += s*v0.w;
        o1.x += s*v1.x; o1.y += s*v1.y; o1.z += s*v1.z; o1.w += s*v1.w;
        o2.x += s*v2.x; o2.y += s*v2.y; o2.z += s*v2.z; o2.w += s*v2.w;
        o3.x += s*v3.x; o3.y += s*v3.y; o3.z += s*v3.z; o3.w += s*v3.w;
    }
    float4* op = (float4*)(attn + (base + (size_t)lane * stride) * 128 + n * 16);
    if (DIRH) {
        op[0] = o0; op[1] = o1; op[2] = o2; op[3] = o3;
    } else {
        float4 e;
        e = op[0]; e.x = 0.5f*(e.x+o0.x); e.y = 0.5f*(e.y+o0.y); e.z = 0.5f*(e.z+o0.z); e.w = 0.5f*(e.w+o0.w); op[0] = e;
        e = op[1]; e.x = 0.5f*(e.x+o1.x); e.y = 0.5f*(e.y+o1.y); e.z = 0.5f*(e.z+o1.z); e.w = 0.5f*(e.w+o1.w); op[1] = e;
        e = op[2]; e.x = 0.5f*(e.x+o2.x); e.y = 0.5f*(e.y+o2.y); e.z = 0.5f*(e.z+o2.z); e.w = 0.5f*(e.w+o2.w); op[2] = e;
        e = op[3]; e.x = 0.5f*(e.x+o3.x); e.y = 0.5f*(e.y+o3.y); e.z = 0.5f*(e.z+o3.z); e.w = 0.5f*(e.w+o3.w); op[3] = e;
    }
}

// ---------------------------------------------------------------------------
extern "C" void kernel_launch(void* const* d_in, const int* in_sizes, int n_in,
                              void* d_out, int out_size, void* d_ws, size_t ws_size,
                              hipStream_t stream)
{
    const float* x      = (const float*)d_in[0];
    const float* cv1_w  = (const float*)d_in[1];
    const float* bn1_g  = (const float*)d_in[2];
    const float* bn1_b  = (const float*)d_in[3];
    const float* bn1_m  = (const float*)d_in[4];
    const float* bn1_v  = (const float*)d_in[5];
    const float* cv2_w  = (const float*)d_in[6];
    const float* bn2_g  = (const float*)d_in[7];
    const float* bn2_b  = (const float*)d_in[8];
    const float* bn2_m  = (const float*)d_in[9];
    const float* bn2_v  = (const float*)d_in[10];
    const float* ln1_g  = (const float*)d_in[11];
    const float* ln1_b  = (const float*)d_in[12];
    const float* qkv_w  = (const float*)d_in[13];
    const float* qkv_b  = (const float*)d_in[14];
    const float* proj_w = (const float*)d_in[15];
    const float* proj_b = (const float*)d_in[16];
    const float* gamma  = (const float*)d_in[17];
    const float* ln2_g  = (const float*)d_in[18];
    const float* ln2_b  = (const float*)d_in[19];
    const float* ffn_w1 = (const float*)d_in[20];
    const float* ffn_b1 = (const float*)d_in[21];
    const float* ffn_w2 = (const float*)d_in[22];
    const float* ffn_b2 = (const float*)d_in[23];

    float* ws   = (float*)d_ws;
    float* y    = ws;                        // N*256 fp32 (y1|y2) NHWC
    float* f    = ws + (size_t)NPOS * 256;   // N*128 fp32 residual
    float* tmp  = ws + (size_t)NPOS * 384;   // N*128 fp32
    float* qkvb = ws + (size_t)NPOS * 512;   // N*384 fp32 (qkv / h1)
    ushort* xT  = (ushort*)qkvb;             // N*256 bf16 (dead after cv1)
    float* out  = (float*)d_out;

    // 0) x NCHW -> xT bf16
    tr_k<<<4096, 256, 0, stream>>>(x, xT);
    // 1) cv1 + BN + SiLU -> y
    gemm_k<256, 256, 1, 1><<<dim3(512, 2), 256, 0, stream>>>(
        nullptr, xT, nullptr, cv1_w, nullptr, bn1_g, bn1_b, bn1_m, bn1_v, y, 256);
    // 2) LN1(y2) -> tmp
    ln_k<<<16384, 256, 0, stream>>>(y + 128, 256, ln1_g, ln1_b, tmp);
    // 3) qkv -> qkvb
    gemm_k<128, 128, 0, 0><<<dim3(512, 3), 256, 0, stream>>>(
        tmp, nullptr, nullptr, qkv_w, qkv_b, nullptr, nullptr, nullptr, nullptr, qkvb, 384);
    // 4) axial attention -> tmp
    attn_k<1><<<2048, 256, 0, stream>>>(qkvb, tmp);
    attn_k<0><<<2048, 256, 0, stream>>>(qkvb, tmp);
    // 5) f = y2 + (attn @ proj^T + b) * gamma
    gemm_k<128, 128, 0, 4><<<dim3(512, 1), 256, 0, stream>>>(
        tmp, nullptr, nullptr, proj_w, proj_b, gamma, y, nullptr, nullptr, f, 128);
    // 6) LN2(f) -> tmp
    ln_k<<<16384, 256, 0, stream>>>(f, 128, ln2_g, ln2_b, tmp);
    // 7) h1 = gelu(...) -> qkvb
    gemm_k<128, 128, 0, 3><<<dim3(512, 2), 256, 0, stream>>>(
        tmp, nullptr, nullptr, ffn_w1, ffn_b1, nullptr, nullptr, nullptr, nullptr, qkvb, 256);
    // 8) f += h1 @ w2^T + b2
    gemm_k<256, 256, 0, 5><<<dim3(512, 1), 256, 0, stream>>>(
        qkvb, nullptr, nullptr, ffn_w2, ffn_b2, nullptr, nullptr, nullptr, nullptr, f, 128);
    // 9) cv2(concat) + BN + SiLU -> out NCHW
    gemm_k<384, 0, 2, 2><<<dim3(512, 2), 256, 0, stream>>>(
        y, nullptr, f, cv2_w, nullptr, bn2_g, bn2_b, bn2_m, bn2_v, out, 0);
}

// Round 3
// 462.470 us; speedup vs baseline: 2.3644x; 1.2543x over previous
//
#include <hip/hip_runtime.h>
#include <math.h>

#define LEPS 1e-5f
static constexpr int NPOS = 65536;   // B*H*W = 16*64*64

typedef __attribute__((ext_vector_type(8))) short short8;
typedef __attribute__((ext_vector_type(4))) float floatx4;

__device__ __forceinline__ ushort f2bf(float f) {
    unsigned int u = __float_as_uint(f);
    u += 0x7FFF + ((u >> 16) & 1);          // RNE
    return (ushort)(u >> 16);
}
__device__ __forceinline__ float bfu(ushort h) {
    return __uint_as_float((unsigned int)h << 16);
}
__device__ __forceinline__ float bfl(unsigned int u) {
    return __uint_as_float(u << 16);
}
__device__ __forceinline__ float bfh(unsigned int u) {
    return __uint_as_float(u & 0xffff0000u);
}

// ---------------------------------------------------------------------------
// Weight fp32 -> bf16, 6 segments (grid.y = segment)
// ---------------------------------------------------------------------------
struct WcvtArgs { const float* src[6]; ushort* dst[6]; int n[6]; };
__global__ __launch_bounds__(256)
void wcvt_k(WcvtArgs a)
{
    const int seg = blockIdx.y;
    const float* s = a.src[seg];
    ushort* d = a.dst[seg];
    const int n = a.n[seg];
    for (int i = blockIdx.x * 256 + threadIdx.x; i < n; i += gridDim.x * 256)
        d[i] = f2bf(s[i]);
}

// BN fold: scale = g*rsqrt(v+eps), shift = b - m*scale
__global__ __launch_bounds__(256)
void bnprep_k(const float* __restrict__ g, const float* __restrict__ b,
              const float* __restrict__ m, const float* __restrict__ v,
              float* __restrict__ scale, float* __restrict__ shift)
{
    const int i = threadIdx.x;
    const float s = g[i] * rsqrtf(v[i] + LEPS);
    scale[i] = s;
    shift[i] = b[i] - m[i] * s;
}

// ---------------------------------------------------------------------------
// x NCHW fp32 -> xT [p][c] bf16  (p = b*4096 + hw)
// ---------------------------------------------------------------------------
__global__ __launch_bounds__(256)
void tr_k(const float* __restrict__ x, ushort* __restrict__ xT)
{
    __shared__ float tile[64][65];
    const int t = threadIdx.x;
    const int bi = blockIdx.x;          // 16 b * 4 ctile * 64 hwtile
    const int hwt = bi & 63, ct = (bi >> 6) & 3, b = bi >> 8;
    const int p0 = b * 4096 + hwt * 64, c0 = ct * 64;
    const float* src = x + ((size_t)(b * 256 + c0) << 12) + hwt * 64;
#pragma unroll
    for (int i = 0; i < 16; i++) {
        int cc = (t >> 6) + i * 4;
        tile[cc][t & 63] = src[((size_t)cc << 12) + (t & 63)];
    }
    __syncthreads();
    const int c2 = (t & 31) * 2;
    const int pr = t >> 5;
#pragma unroll
    for (int i = 0; i < 8; i++) {
        int pp = pr + i * 8;
        unsigned int u = (unsigned int)f2bf(tile[c2][pp])
                       | ((unsigned int)f2bf(tile[c2 + 1][pp]) << 16);
        *(unsigned int*)&xT[(size_t)(p0 + pp) * 256 + c0 + c2] = u;
    }
}

// ---------------------------------------------------------------------------
// MFMA bf16 GEMM, 128x128 tile, BK=64. All A/W inputs bf16.
// AMODE 0: A0 stride ARS.  AMODE 2: concat (k<256: A0 stride 256, else A1 /128)
// EPI 0:+bias->bf16   1:BN(scale,shift)+SiLU->bf16 NHWC
// EPI 2:BN+SiLU->fp32 NCHW (LDS-transposed coalesced store)
// EPI 3:+bias,GELU->bf16   4: res(y2,bf16) + (v+bias)*gamma ->bf16
// EPI 5: out += v+bias (bf16 rmw)
// ---------------------------------------------------------------------------
template<int KDIM, int ARS, int AMODE, int EPI>
__global__ __launch_bounds__(256)
void gemm_k(const ushort* __restrict__ A0, const ushort* __restrict__ A1,
            const ushort* __restrict__ Wm, const float* __restrict__ bias,
            const float* __restrict__ q0, const float* __restrict__ q1,
            const ushort* __restrict__ resh, void* __restrict__ outv, int ors)
{
    __shared__ __align__(16) ushort smem[2 * 128 * 80];   // 40 KB
    ushort (*As)[80] = (ushort (*)[80])smem;
    ushort (*Bs)[80] = (ushort (*)[80])(smem + 128 * 80);
    const int t = threadIdx.x;
    const int p0 = blockIdx.x * 128;
    const int o0 = blockIdx.y * 128;
    const int row = t >> 1, half = t & 1;
    const int lane = t & 63, wv = t >> 6;
    const int wm = (wv & 1) * 64, wn = (wv >> 1) * 64;
    const int ln15 = lane & 15, quad = lane >> 4;
    floatx4 acc[4][4] = {};

    for (int k0 = 0; k0 < KDIM; k0 += 64) {
        // ---- stage A tile (128 x 64 bf16) ----
        {
            const ushort* s;
            if (AMODE == 2) {
                if (k0 < 256) s = A0 + (size_t)(p0 + row) * 256 + k0 + half * 32;
                else          s = A1 + (size_t)(p0 + row) * 128 + (k0 - 256) + half * 32;
            } else {
                s = A0 + (size_t)(p0 + row) * ARS + k0 + half * 32;
            }
#pragma unroll
            for (int i = 0; i < 4; i++)
                *(uint4*)&As[row][half * 32 + i * 8] = ((const uint4*)s)[i];
        }
        // ---- stage W tile (128 x 64 bf16) ----
        {
            const ushort* s = Wm + (size_t)(o0 + row) * KDIM + k0 + half * 32;
#pragma unroll
            for (int i = 0; i < 4; i++)
                *(uint4*)&Bs[row][half * 32 + i * 8] = ((const uint4*)s)[i];
        }
        __syncthreads();
#pragma unroll
        for (int kc = 0; kc < 64; kc += 32) {
            short8 a[4], b[4];
#pragma unroll
            for (int i = 0; i < 4; i++)
                a[i] = *(const short8*)&As[wm + i * 16 + ln15][kc + quad * 8];
#pragma unroll
            for (int j = 0; j < 4; j++)
                b[j] = *(const short8*)&Bs[wn + j * 16 + ln15][kc + quad * 8];
#pragma unroll
            for (int i = 0; i < 4; i++)
#pragma unroll
                for (int j = 0; j < 4; j++)
                    acc[i][j] = __builtin_amdgcn_mfma_f32_16x16x32_bf16(
                        a[i], b[j], acc[i][j], 0, 0, 0);
        }
        __syncthreads();
    }

    if (EPI == 2) {
        // BN+SiLU, then coalesced NCHW fp32 store via LDS transpose
        float* cb = (float*)smem;                       // [64][132]
        float* ob = (float*)outv + (((size_t)(p0 >> 12) * 256) << 12);
        const int hw0 = p0 & 4095;
#pragma unroll
        for (int chunk = 0; chunk < 2; chunk++) {
            __syncthreads();
            if ((wn >> 6) == chunk) {
#pragma unroll
                for (int i = 0; i < 4; i++)
#pragma unroll
                for (int j = 0; j < 4; j++) {
                    const int ch = j * 16 + ln15;
                    const int o = o0 + chunk * 64 + ch;
                    const float sc = q0[o], sh = q1[o];
#pragma unroll
                    for (int r = 0; r < 4; r++) {
                        const int pos = wm + i * 16 + quad * 4 + r;
                        float v = acc[i][j][r] * sc + sh;
                        v = v / (1.f + __expf(-v));
                        cb[ch * 132 + pos] = v;
                    }
                }
            }
            __syncthreads();
#pragma unroll
            for (int it = 0; it < 8; it++) {
                const int flat = it * 1024 + t * 4;
                const int ch = flat >> 7, pos = flat & 127;
                const int o = o0 + chunk * 64 + ch;
                float4 v4 = *(const float4*)&cb[ch * 132 + pos];
                *(float4*)&ob[((size_t)o << 12) + hw0 + pos] = v4;
            }
        }
        return;
    }

    ushort* o16 = (ushort*)outv;
#pragma unroll
    for (int i = 0; i < 4; i++) {
#pragma unroll
        for (int r = 0; r < 4; r++) {
            const int p = p0 + wm + i * 16 + quad * 4 + r;
#pragma unroll
            for (int j = 0; j < 4; j++) {
                const int o = o0 + wn + j * 16 + ln15;
                float v = acc[i][j][r];
                if (EPI == 0) {
                    v += bias[o];
                } else if (EPI == 1) {
                    v = v * q0[o] + q1[o];
                    v = v / (1.f + __expf(-v));
                } else if (EPI == 3) {
                    v += bias[o];
                    v = 0.5f * v * (1.f + erff(v * 0.70710678118654752f));
                } else if (EPI == 4) {
                    v = bfu(resh[(size_t)p * 256 + 128 + o]) + (v + bias[o]) * q0[o];
                } else if (EPI == 5) {
                    v = bfu(o16[(size_t)p * (size_t)ors + o]) + v + bias[o];
                }
                o16[(size_t)p * (size_t)ors + o] = f2bf(v);
            }
        }
    }
}

// ---------------------------------------------------------------------------
// LayerNorm over last dim 128 (bf16 in/out); one wave per position.
// ---------------------------------------------------------------------------
__global__ __launch_bounds__(256)
void ln_k(const ushort* __restrict__ src, int rs,
          const float* __restrict__ g, const float* __restrict__ b,
          ushort* __restrict__ out)
{
    const int lane = threadIdx.x & 63;
    const int p = blockIdx.x * 4 + (threadIdx.x >> 6);
    const unsigned int u = *(const unsigned int*)(src + (size_t)p * rs + lane * 2);
    const float v0 = bfl(u), v1 = bfh(u);
    float s = v0 + v1, s2 = v0 * v0 + v1 * v1;
#pragma unroll
    for (int off = 32; off; off >>= 1) {
        s  += __shfl_down(s, off);
        s2 += __shfl_down(s2, off);
    }
    s = __shfl(s, 0); s2 = __shfl(s2, 0);
    const float mu = s * (1.f / 128.f);
    const float r = rsqrtf(s2 * (1.f / 128.f) - mu * mu + LEPS);
    const float2 gg = *(const float2*)(g + lane * 2);
    const float2 bb = *(const float2*)(b + lane * 2);
    const float o0 = (v0 - mu) * r * gg.x + bb.x;
    const float o1 = (v1 - mu) * r * gg.y + bb.y;
    *(unsigned int*)(out + (size_t)p * 128 + lane * 2) =
        (unsigned int)f2bf(o0) | ((unsigned int)f2bf(o1) << 16);
}

// ---------------------------------------------------------------------------
// Axial decay attention, bf16 I/O. 4 waves/block, one (b,head,line)/wave.
// ---------------------------------------------------------------------------
template<int DIRH>
__global__ __launch_bounds__(256)
void attn_k(const ushort* __restrict__ qkv, ushort* __restrict__ attn)
{
    __shared__ float Ks[4][64][16];
    __shared__ float Vs[4][64][16];
    __shared__ float dpow[64];
    const int t = threadIdx.x, wv = t >> 6, lane = t & 63;
    const int blk = blockIdx.x;               // (b*8+n)*16 + lg
    const int lg = blk & 15, n = (blk >> 4) & 7, b = blk >> 7;
    if (t < 64) {
        const float dec = logf(1.f - exp2f(-2.f - 0.5f * (float)n));
        dpow[t] = __expf(dec * (float)t);
    }
    const int fixed = lg * 4 + wv;
    const int stride = DIRH ? 64 : 1;
    const size_t base = (size_t)b * 4096 + (DIRH ? fixed : fixed * 64);
    const ushort* qp = qkv + (base + (size_t)lane * stride) * 384 + n * 16;
    const uint4 qa = *(const uint4*)qp,         qb = *(const uint4*)(qp + 8);
    const uint4 ka = *(const uint4*)(qp + 128), kb = *(const uint4*)(qp + 136);
    const uint4 va = *(const uint4*)(qp + 256), vb = *(const uint4*)(qp + 264);
    float q[16];
    q[0]=bfl(qa.x); q[1]=bfh(qa.x); q[2]=bfl(qa.y); q[3]=bfh(qa.y);
    q[4]=bfl(qa.z); q[5]=bfh(qa.z); q[6]=bfl(qa.w); q[7]=bfh(qa.w);
    q[8]=bfl(qb.x); q[9]=bfh(qb.x); q[10]=bfl(qb.y); q[11]=bfh(qb.y);
    q[12]=bfl(qb.z); q[13]=bfh(qb.z); q[14]=bfl(qb.w); q[15]=bfh(qb.w);
    float* Kr = Ks[wv][lane];
    float* Vr = Vs[wv][lane];
    Kr[0]=bfl(ka.x); Kr[1]=bfh(ka.x); Kr[2]=bfl(ka.y); Kr[3]=bfh(ka.y);
    Kr[4]=bfl(ka.z); Kr[5]=bfh(ka.z); Kr[6]=bfl(ka.w); Kr[7]=bfh(ka.w);
    Kr[8]=bfl(kb.x); Kr[9]=bfh(kb.x); Kr[10]=bfl(kb.y); Kr[11]=bfh(kb.y);
    Kr[12]=bfl(kb.z); Kr[13]=bfh(kb.z); Kr[14]=bfl(kb.w); Kr[15]=bfh(kb.w);
    Vr[0]=bfl(va.x); Vr[1]=bfh(va.x); Vr[2]=bfl(va.y); Vr[3]=bfh(va.y);
    Vr[4]=bfl(va.z); Vr[5]=bfh(va.z); Vr[6]=bfl(va.w); Vr[7]=bfh(va.w);
    Vr[8]=bfl(vb.x); Vr[9]=bfh(vb.x); Vr[10]=bfl(vb.y); Vr[11]=bfh(vb.y);
    Vr[12]=bfl(vb.z); Vr[13]=bfh(vb.z); Vr[14]=bfl(vb.w); Vr[15]=bfh(vb.w);
    __syncthreads();
    float o[16] = {};
    for (int j = 0; j < 64; j++) {
        const float* kj = Ks[wv][j];
        float s = 0.f;
#pragma unroll
        for (int d = 0; d < 16; d++) s += q[d] * kj[d];
        int dj = lane - j; if (dj < 0) dj = -dj;
        s *= dpow[dj];
        const float* vj = Vs[wv][j];
#pragma unroll
        for (int d = 0; d < 16; d++) o[d] += s * vj[d];
    }
    ushort* op = attn + (base + (size_t)lane * stride) * 128 + n * 16;
    if (!DIRH) {
        const uint4 e0 = *(const uint4*)op, e1 = *(const uint4*)(op + 8);
        const unsigned int eu[8] = { e0.x, e0.y, e0.z, e0.w, e1.x, e1.y, e1.z, e1.w };
#pragma unroll
        for (int i = 0; i < 8; i++) {
            o[2 * i]     = 0.5f * (o[2 * i]     + bfl(eu[i]));
            o[2 * i + 1] = 0.5f * (o[2 * i + 1] + bfh(eu[i]));
        }
    }
    uint4 w0, w1;
    unsigned int* wu0 = (unsigned int*)&w0;
    unsigned int* wu1 = (unsigned int*)&w1;
#pragma unroll
    for (int i = 0; i < 4; i++)
        wu0[i] = (unsigned int)f2bf(o[2 * i]) | ((unsigned int)f2bf(o[2 * i + 1]) << 16);
#pragma unroll
    for (int i = 0; i < 4; i++)
        wu1[i] = (unsigned int)f2bf(o[8 + 2 * i]) | ((unsigned int)f2bf(o[9 + 2 * i]) << 16);
    *(uint4*)op = w0;
    *(uint4*)(op + 8) = w1;
}

// ---------------------------------------------------------------------------
extern "C" void kernel_launch(void* const* d_in, const int* in_sizes, int n_in,
                              void* d_out, int out_size, void* d_ws, size_t ws_size,
                              hipStream_t stream)
{
    const float* x      = (const float*)d_in[0];
    const float* cv1_w  = (const float*)d_in[1];
    const float* bn1_g  = (const float*)d_in[2];
    const float* bn1_b  = (const float*)d_in[3];
    const float* bn1_m  = (const float*)d_in[4];
    const float* bn1_v  = (const float*)d_in[5];
    const float* cv2_w  = (const float*)d_in[6];
    const float* bn2_g  = (const float*)d_in[7];
    const float* bn2_b  = (const float*)d_in[8];
    const float* bn2_m  = (const float*)d_in[9];
    const float* bn2_v  = (const float*)d_in[10];
    const float* ln1_g  = (const float*)d_in[11];
    const float* ln1_b  = (const float*)d_in[12];
    const float* qkv_w  = (const float*)d_in[13];
    const float* qkv_b  = (const float*)d_in[14];
    const float* proj_w = (const float*)d_in[15];
    const float* proj_b = (const float*)d_in[16];
    const float* gamma  = (const float*)d_in[17];
    const float* ln2_g  = (const float*)d_in[18];
    const float* ln2_b  = (const float*)d_in[19];
    const float* ffn_w1 = (const float*)d_in[20];
    const float* ffn_b1 = (const float*)d_in[21];
    const float* ffn_w2 = (const float*)d_in[22];
    const float* ffn_b2 = (const float*)d_in[23];

    ushort* W = (ushort*)d_ws;
    ushort* y    = W;                                  // N*256 bf16
    ushort* f    = y    + (size_t)NPOS * 256;          // N*128
    ushort* tmp  = f    + (size_t)NPOS * 128;          // N*128
    ushort* qkvb = tmp  + (size_t)NPOS * 128;          // N*384
    ushort* xT   = qkvb + (size_t)NPOS * 384;          // N*256
    ushort* wc1  = xT   + (size_t)NPOS * 256;          // 65536
    ushort* wqkv = wc1  + 65536;                       // 49152
    ushort* wpr  = wqkv + 49152;                       // 16384
    ushort* ww1  = wpr  + 16384;                       // 32768
    ushort* ww2  = ww1  + 32768;                       // 32768
    ushort* wc2  = ww2  + 32768;                       // 98304
    float*  bns1 = (float*)(wc2 + 98304);              // 256
    float*  bnb1 = bns1 + 256;
    float*  bns2 = bnb1 + 256;
    float*  bnb2 = bns2 + 256;
    float*  out  = (float*)d_out;

    // 0a) weights -> bf16
    WcvtArgs wa;
    wa.src[0] = cv1_w;  wa.dst[0] = wc1;  wa.n[0] = 65536;
    wa.src[1] = qkv_w;  wa.dst[1] = wqkv; wa.n[1] = 49152;
    wa.src[2] = proj_w; wa.dst[2] = wpr;  wa.n[2] = 16384;
    wa.src[3] = ffn_w1; wa.dst[3] = ww1;  wa.n[3] = 32768;
    wa.src[4] = ffn_w2; wa.dst[4] = ww2;  wa.n[4] = 32768;
    wa.src[5] = cv2_w;  wa.dst[5] = wc2;  wa.n[5] = 98304;
    wcvt_k<<<dim3(96, 6), 256, 0, stream>>>(wa);
    // 0b) fold BN params
    bnprep_k<<<1, 256, 0, stream>>>(bn1_g, bn1_b, bn1_m, bn1_v, bns1, bnb1);
    bnprep_k<<<1, 256, 0, stream>>>(bn2_g, bn2_b, bn2_m, bn2_v, bns2, bnb2);
    // 0c) x NCHW -> xT bf16
    tr_k<<<4096, 256, 0, stream>>>(x, xT);

    // 1) cv1 + BN + SiLU -> y
    gemm_k<256, 256, 0, 1><<<dim3(512, 2), 256, 0, stream>>>(
        xT, nullptr, wc1, nullptr, bns1, bnb1, nullptr, y, 256);
    // 2) LN1(y2) -> tmp
    ln_k<<<16384, 256, 0, stream>>>(y + 128, 256, ln1_g, ln1_b, tmp);
    // 3) qkv -> qkvb
    gemm_k<128, 128, 0, 0><<<dim3(512, 3), 256, 0, stream>>>(
        tmp, nullptr, wqkv, qkv_b, nullptr, nullptr, nullptr, qkvb, 384);
    // 4) axial attention -> tmp
    attn_k<1><<<2048, 256, 0, stream>>>(qkvb, tmp);
    attn_k<0><<<2048, 256, 0, stream>>>(qkvb, tmp);
    // 5) f = y2 + (attn @ proj^T + b) * gamma
    gemm_k<128, 128, 0, 4><<<dim3(512, 1), 256, 0, stream>>>(
        tmp, nullptr, wpr, proj_b, gamma, nullptr, y, f, 128);
    // 6) LN2(f) -> tmp
    ln_k<<<16384, 256, 0, stream>>>(f, 128, ln2_g, ln2_b, tmp);
    // 7) h1 = gelu(fn2 @ w1^T + b1) -> qkvb (reused)
    gemm_k<128, 128, 0, 3><<<dim3(512, 2), 256, 0, stream>>>(
        tmp, nullptr, ww1, ffn_b1, nullptr, nullptr, nullptr, qkvb, 256);
    // 8) f += h1 @ w2^T + b2
    gemm_k<256, 256, 0, 5><<<dim3(512, 1), 256, 0, stream>>>(
        qkvb, nullptr, ww2, ffn_b2, nullptr, nullptr, nullptr, f, 128);
    // 9) cv2(concat[y,f]) + BN + SiLU -> out NCHW fp32
    gemm_k<384, 0, 2, 2><<<dim3(512, 2), 256, 0, stream>>>(
        y, f, wc2, nullptr, bns2, bnb2, nullptr, out, 0);
}

// Round 4
// 413.843 us; speedup vs baseline: 2.6423x; 1.1175x over previous
//
#include <hip/hip_runtime.h>
#include <math.h>

#define LEPS 1e-5f
static constexpr int NPOS = 65536;   // B*H*W = 16*64*64

typedef __attribute__((ext_vector_type(8))) short short8;
typedef __attribute__((ext_vector_type(4))) float floatx4;

__device__ __forceinline__ ushort f2bf(float f) {
    unsigned int u = __float_as_uint(f);
    u += 0x7FFF + ((u >> 16) & 1);          // RNE
    return (ushort)(u >> 16);
}
__device__ __forceinline__ float bfu(ushort h) {
    return __uint_as_float((unsigned int)h << 16);
}
__device__ __forceinline__ float bfl(unsigned int u) {
    return __uint_as_float(u << 16);
}
__device__ __forceinline__ float bfh(unsigned int u) {
    return __uint_as_float(u & 0xffff0000u);
}

// ---------------------------------------------------------------------------
// Weight fp32 -> bf16, 6 segments (grid.y = segment)
// ---------------------------------------------------------------------------
struct WcvtArgs { const float* src[6]; ushort* dst[6]; int n[6]; };
__global__ __launch_bounds__(256)
void wcvt_k(WcvtArgs a)
{
    const int seg = blockIdx.y;
    const float* s = a.src[seg];
    ushort* d = a.dst[seg];
    const int n = a.n[seg];
    for (int i = blockIdx.x * 256 + threadIdx.x; i < n; i += gridDim.x * 256)
        d[i] = f2bf(s[i]);
}

// BN fold: scale = g*rsqrt(v+eps), shift = b - m*scale
__global__ __launch_bounds__(256)
void bnprep_k(const float* __restrict__ g, const float* __restrict__ b,
              const float* __restrict__ m, const float* __restrict__ v,
              float* __restrict__ scale, float* __restrict__ shift)
{
    const int i = threadIdx.x;
    const float s = g[i] * rsqrtf(v[i] + LEPS);
    scale[i] = s;
    shift[i] = b[i] - m[i] * s;
}

// ---------------------------------------------------------------------------
// x NCHW fp32 -> xT [p][c] bf16  (p = b*4096 + hw)
// ---------------------------------------------------------------------------
__global__ __launch_bounds__(256)
void tr_k(const float* __restrict__ x, ushort* __restrict__ xT)
{
    __shared__ float tile[64][65];
    const int t = threadIdx.x;
    const int bi = blockIdx.x;          // 16 b * 4 ctile * 64 hwtile
    const int hwt = bi & 63, ct = (bi >> 6) & 3, b = bi >> 8;
    const int p0 = b * 4096 + hwt * 64, c0 = ct * 64;
    const float* src = x + ((size_t)(b * 256 + c0) << 12) + hwt * 64;
#pragma unroll
    for (int i = 0; i < 16; i++) {
        int cc = (t >> 6) + i * 4;
        tile[cc][t & 63] = src[((size_t)cc << 12) + (t & 63)];
    }
    __syncthreads();
    const int c2 = (t & 31) * 2;
    const int pr = t >> 5;
#pragma unroll
    for (int i = 0; i < 8; i++) {
        int pp = pr + i * 8;
        unsigned int u = (unsigned int)f2bf(tile[c2][pp])
                       | ((unsigned int)f2bf(tile[c2 + 1][pp]) << 16);
        *(unsigned int*)&xT[(size_t)(p0 + pp) * 256 + c0 + c2] = u;
    }
}

// ---------------------------------------------------------------------------
// MFMA bf16 GEMM, 128x128 tile, BK=64. All A/W inputs bf16.
// ---------------------------------------------------------------------------
template<int KDIM, int ARS, int AMODE, int EPI>
__global__ __launch_bounds__(256)
void gemm_k(const ushort* __restrict__ A0, const ushort* __restrict__ A1,
            const ushort* __restrict__ Wm, const float* __restrict__ bias,
            const float* __restrict__ q0, const float* __restrict__ q1,
            const ushort* __restrict__ resh, void* __restrict__ outv, int ors)
{
    __shared__ __align__(16) ushort smem[2 * 128 * 80];   // 40 KB
    ushort (*As)[80] = (ushort (*)[80])smem;
    ushort (*Bs)[80] = (ushort (*)[80])(smem + 128 * 80);
    const int t = threadIdx.x;
    const int p0 = blockIdx.x * 128;
    const int o0 = blockIdx.y * 128;
    const int row = t >> 1, half = t & 1;
    const int lane = t & 63, wv = t >> 6;
    const int wm = (wv & 1) * 64, wn = (wv >> 1) * 64;
    const int ln15 = lane & 15, quad = lane >> 4;
    floatx4 acc[4][4] = {};

    for (int k0 = 0; k0 < KDIM; k0 += 64) {
        {
            const ushort* s;
            if (AMODE == 2) {
                if (k0 < 256) s = A0 + (size_t)(p0 + row) * 256 + k0 + half * 32;
                else          s = A1 + (size_t)(p0 + row) * 128 + (k0 - 256) + half * 32;
            } else {
                s = A0 + (size_t)(p0 + row) * ARS + k0 + half * 32;
            }
#pragma unroll
            for (int i = 0; i < 4; i++)
                *(uint4*)&As[row][half * 32 + i * 8] = ((const uint4*)s)[i];
        }
        {
            const ushort* s = Wm + (size_t)(o0 + row) * KDIM + k0 + half * 32;
#pragma unroll
            for (int i = 0; i < 4; i++)
                *(uint4*)&Bs[row][half * 32 + i * 8] = ((const uint4*)s)[i];
        }
        __syncthreads();
#pragma unroll
        for (int kc = 0; kc < 64; kc += 32) {
            short8 a[4], b[4];
#pragma unroll
            for (int i = 0; i < 4; i++)
                a[i] = *(const short8*)&As[wm + i * 16 + ln15][kc + quad * 8];
#pragma unroll
            for (int j = 0; j < 4; j++)
                b[j] = *(const short8*)&Bs[wn + j * 16 + ln15][kc + quad * 8];
#pragma unroll
            for (int i = 0; i < 4; i++)
#pragma unroll
                for (int j = 0; j < 4; j++)
                    acc[i][j] = __builtin_amdgcn_mfma_f32_16x16x32_bf16(
                        a[i], b[j], acc[i][j], 0, 0, 0);
        }
        __syncthreads();
    }

    if (EPI == 2) {
        float* cb = (float*)smem;                       // [64][132]
        float* ob = (float*)outv + (((size_t)(p0 >> 12) * 256) << 12);
        const int hw0 = p0 & 4095;
#pragma unroll
        for (int chunk = 0; chunk < 2; chunk++) {
            __syncthreads();
            if ((wn >> 6) == chunk) {
#pragma unroll
                for (int i = 0; i < 4; i++)
#pragma unroll
                for (int j = 0; j < 4; j++) {
                    const int ch = j * 16 + ln15;
                    const int o = o0 + chunk * 64 + ch;
                    const float sc = q0[o], sh = q1[o];
#pragma unroll
                    for (int r = 0; r < 4; r++) {
                        const int pos = wm + i * 16 + quad * 4 + r;
                        float v = acc[i][j][r] * sc + sh;
                        v = v / (1.f + __expf(-v));
                        cb[ch * 132 + pos] = v;
                    }
                }
            }
            __syncthreads();
#pragma unroll
            for (int it = 0; it < 8; it++) {
                const int flat = it * 1024 + t * 4;
                const int ch = flat >> 7, pos = flat & 127;
                const int o = o0 + chunk * 64 + ch;
                float4 v4 = *(const float4*)&cb[ch * 132 + pos];
                *(float4*)&ob[((size_t)o << 12) + hw0 + pos] = v4;
            }
        }
        return;
    }

    ushort* o16 = (ushort*)outv;
#pragma unroll
    for (int i = 0; i < 4; i++) {
#pragma unroll
        for (int r = 0; r < 4; r++) {
            const int p = p0 + wm + i * 16 + quad * 4 + r;
#pragma unroll
            for (int j = 0; j < 4; j++) {
                const int o = o0 + wn + j * 16 + ln15;
                float v = acc[i][j][r];
                if (EPI == 0) {
                    v += bias[o];
                } else if (EPI == 1) {
                    v = v * q0[o] + q1[o];
                    v = v / (1.f + __expf(-v));
                } else if (EPI == 3) {
                    v += bias[o];
                    v = 0.5f * v * (1.f + erff(v * 0.70710678118654752f));
                } else if (EPI == 4) {
                    v = bfu(resh[(size_t)p * 256 + 128 + o]) + (v + bias[o]) * q0[o];
                } else if (EPI == 5) {
                    v = bfu(o16[(size_t)p * (size_t)ors + o]) + v + bias[o];
                }
                o16[(size_t)p * (size_t)ors + o] = f2bf(v);
            }
        }
    }
}

// ---------------------------------------------------------------------------
// LayerNorm over last dim 128 (bf16 in/out); one wave per position.
// ---------------------------------------------------------------------------
__global__ __launch_bounds__(256)
void ln_k(const ushort* __restrict__ src, int rs,
          const float* __restrict__ g, const float* __restrict__ b,
          ushort* __restrict__ out)
{
    const int lane = threadIdx.x & 63;
    const int p = blockIdx.x * 4 + (threadIdx.x >> 6);
    const unsigned int u = *(const unsigned int*)(src + (size_t)p * rs + lane * 2);
    const float v0 = bfl(u), v1 = bfh(u);
    float s = v0 + v1, s2 = v0 * v0 + v1 * v1;
#pragma unroll
    for (int off = 32; off; off >>= 1) {
        s  += __shfl_down(s, off);
        s2 += __shfl_down(s2, off);
    }
    s = __shfl(s, 0); s2 = __shfl(s2, 0);
    const float mu = s * (1.f / 128.f);
    const float r = rsqrtf(s2 * (1.f / 128.f) - mu * mu + LEPS);
    const float2 gg = *(const float2*)(g + lane * 2);
    const float2 bb = *(const float2*)(b + lane * 2);
    const float o0 = (v0 - mu) * r * gg.x + bb.x;
    const float o1 = (v1 - mu) * r * gg.y + bb.y;
    *(unsigned int*)(out + (size_t)p * 128 + lane * 2) =
        (unsigned int)f2bf(o0) | ((unsigned int)f2bf(o1) << 16);
}

// ---------------------------------------------------------------------------
// MFMA axial decay attention. 4 waves/block, one (b,head,line) per wave.
// Per line: S = Q(64x16) K^T (16 MFMAs, K padded to 32), decay via LDS LUT,
// S->LDS bf16 row-major, O^T = V^T(16x64) S^T via 8 MFMAs, packed stores.
// DIRH=1 along H (writes), DIRH=0 along W (merges 0.5*(old+new)).
// ---------------------------------------------------------------------------
template<int DIRH>
__global__ __launch_bounds__(256)
void attn_k(const ushort* __restrict__ qkv, ushort* __restrict__ attn)
{
    __shared__ ushort VtS[4][16 * 72];    // V^T [d][j], stride 72
    __shared__ ushort SbS[4][64 * 72];    // S   [i][j], stride 72
    __shared__ float dpow[128];           // dpow[k] = e^{dec*|k-63|}
    const int t = threadIdx.x, wv = t >> 6, lane = t & 63;
    const int ln15 = lane & 15, quad = lane >> 4;
    const int blk = blockIdx.x;               // (b*8+n)*16 + lg
    const int lg = blk & 15, n = (blk >> 4) & 7, b = blk >> 7;
    if (t < 128) {
        const float dec = logf(1.f - exp2f(-2.f - 0.5f * (float)n));
        int d = t - 63; if (d < 0) d = -d;
        dpow[t] = __expf(dec * (float)d);
    }
    const int fixed = lg * 4 + wv;
    const int stride = DIRH ? 64 : 1;
    const size_t base = (size_t)b * 4096 + (DIRH ? fixed : fixed * 64);
    const size_t cbase = base * 384 + n * 16;

    // ---- stage V^T into LDS (lane = position j) ----
    {
        const ushort* vp = qkv + cbase + (size_t)lane * stride * 384 + 256;
        const uint4 va = *(const uint4*)vp, vb = *(const uint4*)(vp + 8);
        ushort* vt = VtS[wv] + lane;
        const unsigned int w[8] = { va.x, va.y, va.z, va.w, vb.x, vb.y, vb.z, vb.w };
#pragma unroll
        for (int d = 0; d < 8; d++) {
            vt[(2 * d) * 72]     = (ushort)(w[d] & 0xffff);
            vt[(2 * d + 1) * 72] = (ushort)(w[d] >> 16);
        }
    }
    // ---- load Q/K fragments (A/B of 16x16x32, K dim padded 16->32) ----
    short8 qa[4], kb[4];
    {
        const short8 z = {0, 0, 0, 0, 0, 0, 0, 0};
#pragma unroll
        for (int mt = 0; mt < 4; mt++) {
            const int i = mt * 16 + ln15;
            if (quad < 2) {
                const ushort* qp = qkv + cbase + (size_t)i * stride * 384 + quad * 8;
                qa[mt] = *(const short8*)qp;
                kb[mt] = *(const short8*)(qp + 128);
            } else { qa[mt] = z; kb[mt] = z; }
        }
    }
    __syncthreads();

    // ---- QK^T + decay -> Sb (bf16 row-major) ----
#pragma unroll
    for (int mt = 0; mt < 4; mt++) {
#pragma unroll
        for (int nt = 0; nt < 4; nt++) {
            floatx4 c = {0.f, 0.f, 0.f, 0.f};
            c = __builtin_amdgcn_mfma_f32_16x16x32_bf16(qa[mt], kb[nt], c, 0, 0, 0);
            const int i0 = mt * 16 + quad * 4;
            const int jl = nt * 16 + ln15;
            const float* lut = dpow + (i0 - jl + 63);
            ushort* sb = SbS[wv] + i0 * 72 + jl;
#pragma unroll
            for (int r = 0; r < 4; r++)
                sb[r * 72] = f2bf(c[r] * lut[r]);
        }
    }
    __syncthreads();

    // ---- O^T = V^T * S^T  (M=16 d, N=64 i, K=64 j) ----
    short8 av[2];
#pragma unroll
    for (int c = 0; c < 2; c++)
        av[c] = *(const short8*)&VtS[wv][ln15 * 72 + c * 32 + quad * 8];
    floatx4 o[4] = {};
#pragma unroll
    for (int nt4 = 0; nt4 < 4; nt4++) {
#pragma unroll
        for (int c = 0; c < 2; c++) {
            const short8 bs = *(const short8*)
                &SbS[wv][(nt4 * 16 + ln15) * 72 + c * 32 + quad * 8];
            o[nt4] = __builtin_amdgcn_mfma_f32_16x16x32_bf16(av[c], bs, o[nt4], 0, 0, 0);
        }
    }
    // ---- store: lane holds O[i = nt4*16+ln15][d = quad*4 + 0..3] ----
#pragma unroll
    for (int nt4 = 0; nt4 < 4; nt4++) {
        const int i = nt4 * 16 + ln15;
        ushort* op = attn + (base + (size_t)i * stride) * 128 + n * 16 + quad * 4;
        float v0 = o[nt4][0], v1 = o[nt4][1], v2 = o[nt4][2], v3 = o[nt4][3];
        if (!DIRH) {
            const uint2 e = *(const uint2*)op;
            v0 = 0.5f * (v0 + bfl(e.x)); v1 = 0.5f * (v1 + bfh(e.x));
            v2 = 0.5f * (v2 + bfl(e.y)); v3 = 0.5f * (v3 + bfh(e.y));
        }
        uint2 w;
        w.x = (unsigned int)f2bf(v0) | ((unsigned int)f2bf(v1) << 16);
        w.y = (unsigned int)f2bf(v2) | ((unsigned int)f2bf(v3) << 16);
        *(uint2*)op = w;
    }
}

// ---------------------------------------------------------------------------
extern "C" void kernel_launch(void* const* d_in, const int* in_sizes, int n_in,
                              void* d_out, int out_size, void* d_ws, size_t ws_size,
                              hipStream_t stream)
{
    const float* x      = (const float*)d_in[0];
    const float* cv1_w  = (const float*)d_in[1];
    const float* bn1_g  = (const float*)d_in[2];
    const float* bn1_b  = (const float*)d_in[3];
    const float* bn1_m  = (const float*)d_in[4];
    const float* bn1_v  = (const float*)d_in[5];
    const float* cv2_w  = (const float*)d_in[6];
    const float* bn2_g  = (const float*)d_in[7];
    const float* bn2_b  = (const float*)d_in[8];
    const float* bn2_m  = (const float*)d_in[9];
    const float* bn2_v  = (const float*)d_in[10];
    const float* ln1_g  = (const float*)d_in[11];
    const float* ln1_b  = (const float*)d_in[12];
    const float* qkv_w  = (const float*)d_in[13];
    const float* qkv_b  = (const float*)d_in[14];
    const float* proj_w = (const float*)d_in[15];
    const float* proj_b = (const float*)d_in[16];
    const float* gamma  = (const float*)d_in[17];
    const float* ln2_g  = (const float*)d_in[18];
    const float* ln2_b  = (const float*)d_in[19];
    const float* ffn_w1 = (const float*)d_in[20];
    const float* ffn_b1 = (const float*)d_in[21];
    const float* ffn_w2 = (const float*)d_in[22];
    const float* ffn_b2 = (const float*)d_in[23];

    ushort* W = (ushort*)d_ws;
    ushort* y    = W;                                  // N*256 bf16
    ushort* f    = y    + (size_t)NPOS * 256;          // N*128
    ushort* tmp  = f    + (size_t)NPOS * 128;          // N*128
    ushort* qkvb = tmp  + (size_t)NPOS * 128;          // N*384
    ushort* xT   = qkvb + (size_t)NPOS * 384;          // N*256
    ushort* wc1  = xT   + (size_t)NPOS * 256;          // 65536
    ushort* wqkv = wc1  + 65536;                       // 49152
    ushort* wpr  = wqkv + 49152;                       // 16384
    ushort* ww1  = wpr  + 16384;                       // 32768
    ushort* ww2  = ww1  + 32768;                       // 32768
    ushort* wc2  = ww2  + 32768;                       // 98304
    float*  bns1 = (float*)(wc2 + 98304);              // 256
    float*  bnb1 = bns1 + 256;
    float*  bns2 = bnb1 + 256;
    float*  bnb2 = bns2 + 256;
    float*  out  = (float*)d_out;

    WcvtArgs wa;
    wa.src[0] = cv1_w;  wa.dst[0] = wc1;  wa.n[0] = 65536;
    wa.src[1] = qkv_w;  wa.dst[1] = wqkv; wa.n[1] = 49152;
    wa.src[2] = proj_w; wa.dst[2] = wpr;  wa.n[2] = 16384;
    wa.src[3] = ffn_w1; wa.dst[3] = ww1;  wa.n[3] = 32768;
    wa.src[4] = ffn_w2; wa.dst[4] = ww2;  wa.n[4] = 32768;
    wa.src[5] = cv2_w;  wa.dst[5] = wc2;  wa.n[5] = 98304;
    wcvt_k<<<dim3(96, 6), 256, 0, stream>>>(wa);
    bnprep_k<<<1, 256, 0, stream>>>(bn1_g, bn1_b, bn1_m, bn1_v, bns1, bnb1);
    bnprep_k<<<1, 256, 0, stream>>>(bn2_g, bn2_b, bn2_m, bn2_v, bns2, bnb2);
    tr_k<<<4096, 256, 0, stream>>>(x, xT);

    // 1) cv1 + BN + SiLU -> y
    gemm_k<256, 256, 0, 1><<<dim3(512, 2), 256, 0, stream>>>(
        xT, nullptr, wc1, nullptr, bns1, bnb1, nullptr, y, 256);
    // 2) LN1(y2) -> tmp
    ln_k<<<16384, 256, 0, stream>>>(y + 128, 256, ln1_g, ln1_b, tmp);
    // 3) qkv -> qkvb
    gemm_k<128, 128, 0, 0><<<dim3(512, 3), 256, 0, stream>>>(
        tmp, nullptr, wqkv, qkv_b, nullptr, nullptr, nullptr, qkvb, 384);
    // 4) axial attention -> tmp
    attn_k<1><<<2048, 256, 0, stream>>>(qkvb, tmp);
    attn_k<0><<<2048, 256, 0, stream>>>(qkvb, tmp);
    // 5) f = y2 + (attn @ proj^T + b) * gamma
    gemm_k<128, 128, 0, 4><<<dim3(512, 1), 256, 0, stream>>>(
        tmp, nullptr, wpr, proj_b, gamma, nullptr, y, f, 128);
    // 6) LN2(f) -> tmp
    ln_k<<<16384, 256, 0, stream>>>(f, 128, ln2_g, ln2_b, tmp);
    // 7) h1 = gelu(fn2 @ w1^T + b1) -> qkvb (reused)
    gemm_k<128, 128, 0, 3><<<dim3(512, 2), 256, 0, stream>>>(
        tmp, nullptr, ww1, ffn_b1, nullptr, nullptr, nullptr, qkvb, 256);
    // 8) f += h1 @ w2^T + b2
    gemm_k<256, 256, 0, 5><<<dim3(512, 1), 256, 0, stream>>>(
        qkvb, nullptr, ww2, ffn_b2, nullptr, nullptr, nullptr, f, 128);
    // 9) cv2(concat[y,f]) + BN + SiLU -> out NCHW fp32
    gemm_k<384, 0, 2, 2><<<dim3(512, 2), 256, 0, stream>>>(
        y, f, wc2, nullptr, bns2, bnb2, nullptr, out, 0);
}

// Round 5
// 367.860 us; speedup vs baseline: 2.9725x; 1.1250x over previous
//
#include <hip/hip_runtime.h>
#include <math.h>

#define LEPS 1e-5f
static constexpr int NPOS = 65536;   // B*H*W = 16*64*64

typedef __attribute__((ext_vector_type(8))) short short8;
typedef __attribute__((ext_vector_type(4))) float floatx4;

__device__ __forceinline__ ushort f2bf(float f) {
    unsigned int u = __float_as_uint(f);
    u += 0x7FFF + ((u >> 16) & 1);          // RNE
    return (ushort)(u >> 16);
}
__device__ __forceinline__ float bfu(ushort h) {
    return __uint_as_float((unsigned int)h << 16);
}
__device__ __forceinline__ float bfl(unsigned int u) {
    return __uint_as_float(u << 16);
}
__device__ __forceinline__ float bfh(unsigned int u) {
    return __uint_as_float(u & 0xffff0000u);
}

// ---------------------------------------------------------------------------
// Weight fp32 -> bf16, 6 segments (grid.y = segment)
// ---------------------------------------------------------------------------
struct WcvtArgs { const float* src[6]; ushort* dst[6]; int n[6]; };
__global__ __launch_bounds__(256)
void wcvt_k(WcvtArgs a)
{
    const int seg = blockIdx.y;
    const float* s = a.src[seg];
    ushort* d = a.dst[seg];
    const int n = a.n[seg];
    for (int i = blockIdx.x * 256 + threadIdx.x; i < n; i += gridDim.x * 256)
        d[i] = f2bf(s[i]);
}

// BN fold for both BNs in one launch (grid.x = which)
__global__ __launch_bounds__(256)
void bnprep_k(const float* g1, const float* b1, const float* m1, const float* v1,
              const float* g2, const float* b2, const float* m2, const float* v2,
              float* s1, float* h1, float* s2, float* h2)
{
    const int i = threadIdx.x;
    if (blockIdx.x == 0) {
        const float s = g1[i] * rsqrtf(v1[i] + LEPS);
        s1[i] = s; h1[i] = b1[i] - m1[i] * s;
    } else {
        const float s = g2[i] * rsqrtf(v2[i] + LEPS);
        s2[i] = s; h2[i] = b2[i] - m2[i] * s;
    }
}

// ---------------------------------------------------------------------------
// x NCHW fp32 -> xT [p][c] bf16  (p = b*4096 + hw)
// ---------------------------------------------------------------------------
__global__ __launch_bounds__(256)
void tr_k(const float* __restrict__ x, ushort* __restrict__ xT)
{
    __shared__ float tile[64][65];
    const int t = threadIdx.x;
    const int bi = blockIdx.x;          // 16 b * 4 ctile * 64 hwtile
    const int hwt = bi & 63, ct = (bi >> 6) & 3, b = bi >> 8;
    const int p0 = b * 4096 + hwt * 64, c0 = ct * 64;
    const float* src = x + ((size_t)(b * 256 + c0) << 12) + hwt * 64;
#pragma unroll
    for (int i = 0; i < 16; i++) {
        int cc = (t >> 6) + i * 4;
        tile[cc][t & 63] = src[((size_t)cc << 12) + (t & 63)];
    }
    __syncthreads();
    const int c2 = (t & 31) * 2;
    const int pr = t >> 5;
#pragma unroll
    for (int i = 0; i < 8; i++) {
        int pp = pr + i * 8;
        unsigned int u = (unsigned int)f2bf(tile[c2][pp])
                       | ((unsigned int)f2bf(tile[c2 + 1][pp]) << 16);
        *(unsigned int*)&xT[(size_t)(p0 + pp) * 256 + c0 + c2] = u;
    }
}

// ---------------------------------------------------------------------------
// MFMA bf16 GEMM, 128x128 tile, BK=64, LDS pad 72 (conflict-free groups).
// AMODE 0: A0 stride ARS.  AMODE 2: concat.  AMODE 3: avg(A0,A1) stride 128.
// EPI 0:+bias->bf16  1:BN+SiLU->bf16 (cv1)  2:BN+SiLU->fp32 NCHW (cv2)
// EPI 4: res(y2) + (v+bias)*gamma -> bf16 (proj)
// LN=1: additionally LayerNorm each 128-ch row of this tile -> lnout
//       (cv1: only for o-tile 1 = y2; proj: always)
// ---------------------------------------------------------------------------
template<int KDIM, int ARS, int AMODE, int EPI, int LN>
__global__ __launch_bounds__(256)
void gemm_k(const ushort* __restrict__ A0, const ushort* __restrict__ A1,
            const ushort* __restrict__ Wm, const float* __restrict__ bias,
            const float* __restrict__ q0, const float* __restrict__ q1,
            const ushort* __restrict__ resh,
            const float* __restrict__ lng, const float* __restrict__ lnb,
            ushort* __restrict__ lnout, void* __restrict__ outv, int ors)
{
    __shared__ __align__(16) ushort smem[2 * 128 * 72];   // 36.9 KB
    ushort (*As)[72] = (ushort (*)[72])smem;
    ushort (*Bs)[72] = (ushort (*)[72])(smem + 128 * 72);
    const int t = threadIdx.x;
    const int p0 = blockIdx.x * 128;
    const int o0 = blockIdx.y * 128;
    const int row = t >> 1, half = t & 1;
    const int lane = t & 63, wv = t >> 6;
    const int wm = (wv & 1) * 64, wn = (wv >> 1) * 64;
    const int ln15 = lane & 15, quad = lane >> 4;
    floatx4 acc[4][4] = {};

    for (int k0 = 0; k0 < KDIM; k0 += 64) {
        // ---- stage A tile (128 x 64 bf16) ----
        if (AMODE == 3) {
            const ushort* s1 = A0 + (size_t)(p0 + row) * 128 + k0 + half * 32;
            const ushort* s2 = A1 + (size_t)(p0 + row) * 128 + k0 + half * 32;
#pragma unroll
            for (int i = 0; i < 4; i++) {
                uint4 ua = ((const uint4*)s1)[i];
                uint4 ub = ((const uint4*)s2)[i];
                const unsigned int* ap = (const unsigned int*)&ua;
                const unsigned int* bp = (const unsigned int*)&ub;
                uint4 w;
                unsigned int* wp = (unsigned int*)&w;
#pragma unroll
                for (int j = 0; j < 4; j++)
                    wp[j] = (unsigned int)f2bf(0.5f * (bfl(ap[j]) + bfl(bp[j])))
                          | ((unsigned int)f2bf(0.5f * (bfh(ap[j]) + bfh(bp[j]))) << 16);
                *(uint4*)&As[row][half * 32 + i * 8] = w;
            }
        } else {
            const ushort* s;
            if (AMODE == 2) {
                if (k0 < 256) s = A0 + (size_t)(p0 + row) * 256 + k0 + half * 32;
                else          s = A1 + (size_t)(p0 + row) * 128 + (k0 - 256) + half * 32;
            } else {
                s = A0 + (size_t)(p0 + row) * ARS + k0 + half * 32;
            }
#pragma unroll
            for (int i = 0; i < 4; i++)
                *(uint4*)&As[row][half * 32 + i * 8] = ((const uint4*)s)[i];
        }
        // ---- stage W tile (128 x 64 bf16) ----
        {
            const ushort* s = Wm + (size_t)(o0 + row) * KDIM + k0 + half * 32;
#pragma unroll
            for (int i = 0; i < 4; i++)
                *(uint4*)&Bs[row][half * 32 + i * 8] = ((const uint4*)s)[i];
        }
        __syncthreads();
#pragma unroll
        for (int kc = 0; kc < 64; kc += 32) {
            short8 a[4], b[4];
#pragma unroll
            for (int i = 0; i < 4; i++)
                a[i] = *(const short8*)&As[wm + i * 16 + ln15][kc + quad * 8];
#pragma unroll
            for (int j = 0; j < 4; j++)
                b[j] = *(const short8*)&Bs[wn + j * 16 + ln15][kc + quad * 8];
#pragma unroll
            for (int i = 0; i < 4; i++)
#pragma unroll
                for (int j = 0; j < 4; j++)
                    acc[i][j] = __builtin_amdgcn_mfma_f32_16x16x32_bf16(
                        a[i], b[j], acc[i][j], 0, 0, 0);
        }
        __syncthreads();
    }

    if (EPI == 2) {
        // BN+SiLU, coalesced NCHW fp32 store via LDS transpose
        float* cb = (float*)smem;                       // [64][132]
        float* ob = (float*)outv + (((size_t)(p0 >> 12) * 256) << 12);
        const int hw0 = p0 & 4095;
#pragma unroll
        for (int chunk = 0; chunk < 2; chunk++) {
            __syncthreads();
            if ((wn >> 6) == chunk) {
#pragma unroll
                for (int i = 0; i < 4; i++)
#pragma unroll
                for (int j = 0; j < 4; j++) {
                    const int ch = j * 16 + ln15;
                    const int o = o0 + chunk * 64 + ch;
                    const float sc = q0[o], sh = q1[o];
#pragma unroll
                    for (int r = 0; r < 4; r++) {
                        const int pos = wm + i * 16 + quad * 4 + r;
                        float v = acc[i][j][r] * sc + sh;
                        v = v / (1.f + __expf(-v));
                        cb[ch * 132 + pos] = v;
                    }
                }
            }
            __syncthreads();
#pragma unroll
            for (int it = 0; it < 8; it++) {
                const int flat = it * 1024 + t * 4;
                const int ch = flat >> 7, pos = flat & 127;
                const int o = o0 + chunk * 64 + ch;
                float4 v4 = *(const float4*)&cb[ch * 132 + pos];
                *(float4*)&ob[((size_t)o << 12) + hw0 + pos] = v4;
            }
        }
        return;
    }

    const bool lnact = LN && (EPI != 1 || o0 == 128);
    ushort (*lt)[136] = (ushort (*)[136])smem;          // 128 x 136 = 34.8 KB
    ushort* o16 = (ushort*)outv;
#pragma unroll
    for (int i = 0; i < 4; i++) {
#pragma unroll
        for (int r = 0; r < 4; r++) {
            const int p = p0 + wm + i * 16 + quad * 4 + r;
#pragma unroll
            for (int j = 0; j < 4; j++) {
                const int ol = wn + j * 16 + ln15;
                const int o = o0 + ol;
                float v = acc[i][j][r];
                if (EPI == 0) {
                    v += bias[o];
                } else if (EPI == 1) {
                    v = v * q0[o] + q1[o];
                    v = v / (1.f + __expf(-v));
                } else if (EPI == 4) {
                    v = bfu(resh[(size_t)p * 256 + 128 + o]) + (v + bias[o]) * q0[o];
                }
                const ushort hv = f2bf(v);
                o16[(size_t)p * (size_t)ors + o] = hv;
                if (lnact) lt[p - p0][ol] = hv;
            }
        }
    }

    if (lnact) {
        __syncthreads();
        const int rrow = t >> 1, rhalf = t & 1;
        const ushort* rp = &lt[rrow][rhalf * 64];
        float s = 0.f, s2 = 0.f;
#pragma unroll
        for (int i = 0; i < 8; i++) {
            const uint4 u = *(const uint4*)(rp + i * 8);
            const unsigned int ww[4] = {u.x, u.y, u.z, u.w};
#pragma unroll
            for (int j = 0; j < 4; j++) {
                const float a = bfl(ww[j]), c = bfh(ww[j]);
                s += a + c; s2 += a * a + c * c;
            }
        }
        s += __shfl_xor(s, 1); s2 += __shfl_xor(s2, 1);
        const float mu = s * (1.f / 128.f);
        const float rn = rsqrtf(s2 * (1.f / 128.f) - mu * mu + LEPS);
        ushort* op = lnout + (size_t)(p0 + rrow) * 128 + rhalf * 64;
#pragma unroll
        for (int i = 0; i < 8; i++) {
            const uint4 u = *(const uint4*)(rp + i * 8);
            const unsigned int ww[4] = {u.x, u.y, u.z, u.w};
            uint4 wout;
            unsigned int* wo = (unsigned int*)&wout;
#pragma unroll
            for (int j = 0; j < 4; j++) {
                const int ch = rhalf * 64 + i * 8 + j * 2;
                const float2 gg = *(const float2*)(lng + ch);
                const float2 bb = *(const float2*)(lnb + ch);
                const float a = (bfl(ww[j]) - mu) * rn * gg.x + bb.x;
                const float c = (bfh(ww[j]) - mu) * rn * gg.y + bb.y;
                wo[j] = (unsigned int)f2bf(a) | ((unsigned int)f2bf(c) << 16);
            }
            *(uint4*)(op + i * 8) = wout;
        }
    }
}

// ---------------------------------------------------------------------------
// Fused FFN: f += W2 @ gelu(W1 @ fn2 + b1) + b2.  64 positions/block,
// h1 (64x256) lives in LDS.  ~78 KB LDS -> 2 blocks/CU.
// ---------------------------------------------------------------------------
__global__ __launch_bounds__(256)
void ffn_k(const ushort* __restrict__ fn2, const ushort* __restrict__ w1,
           const float* __restrict__ b1, const ushort* __restrict__ w2,
           const float* __restrict__ b2, ushort* __restrict__ f)
{
    __shared__ __align__(16) ushort smem[64 * 72 + 256 * 72 + 64 * 264];
    ushort (*Ax)[72]  = (ushort (*)[72])smem;                  // 64 x 72
    ushort (*Wt)[72]  = (ushort (*)[72])(smem + 64 * 72);      // 256 x 72
    ushort (*H1)[264] = (ushort (*)[264])(smem + 64 * 72 + 256 * 72); // 64 x 264
    const int t = threadIdx.x;
    const int p0 = blockIdx.x * 64;
    const int lane = t & 63, wv = t >> 6;
    const int ln15 = lane & 15, quad = lane >> 4;

    // ---- GEMM1: h1[64][256] = gelu(fn2 @ w1^T + b1), wave wv -> ch [wv*64,+64)
    floatx4 acc1[4][4] = {};
    for (int k0 = 0; k0 < 128; k0 += 64) {
#pragma unroll
        for (int u = 0; u < 2; u++) {
            const int fi = t * 2 + u, r = fi >> 3, c = (fi & 7) * 8;
            *(uint4*)&Ax[r][c] = *(const uint4*)(fn2 + (size_t)(p0 + r) * 128 + k0 + c);
        }
#pragma unroll
        for (int u = 0; u < 8; u++)
            *(uint4*)&Wt[t][u * 8] = *(const uint4*)(w1 + (size_t)t * 128 + k0 + u * 8);
        __syncthreads();
#pragma unroll
        for (int kc = 0; kc < 64; kc += 32) {
            short8 a[4], b[4];
#pragma unroll
            for (int i = 0; i < 4; i++)
                a[i] = *(const short8*)&Ax[i * 16 + ln15][kc + quad * 8];
#pragma unroll
            for (int j = 0; j < 4; j++)
                b[j] = *(const short8*)&Wt[wv * 64 + j * 16 + ln15][kc + quad * 8];
#pragma unroll
            for (int i = 0; i < 4; i++)
#pragma unroll
                for (int j = 0; j < 4; j++)
                    acc1[i][j] = __builtin_amdgcn_mfma_f32_16x16x32_bf16(
                        a[i], b[j], acc1[i][j], 0, 0, 0);
        }
        __syncthreads();
    }
    {
        float bb1[4];
#pragma unroll
        for (int j = 0; j < 4; j++) bb1[j] = b1[wv * 64 + j * 16 + ln15];
#pragma unroll
        for (int i = 0; i < 4; i++)
#pragma unroll
        for (int j = 0; j < 4; j++)
#pragma unroll
        for (int r = 0; r < 4; r++) {
            float v = acc1[i][j][r] + bb1[j];
            v = 0.5f * v * (1.f + erff(v * 0.70710678118654752f));
            H1[i * 16 + quad * 4 + r][wv * 64 + j * 16 + ln15] = f2bf(v);
        }
    }
    __syncthreads();

    // ---- GEMM2: fo[64][128] = h1 @ w2^T, wave wv -> ch [wv*32,+32)
    floatx4 acc2[4][2] = {};
    for (int k0 = 0; k0 < 256; k0 += 64) {
#pragma unroll
        for (int u = 0; u < 4; u++) {
            const int fi = t * 4 + u, r = fi >> 3, c = (fi & 7) * 8;
            *(uint4*)&Wt[r][c] = *(const uint4*)(w2 + (size_t)r * 256 + k0 + c);
        }
        __syncthreads();
#pragma unroll
        for (int kc = 0; kc < 64; kc += 32) {
            short8 a[4], b[2];
#pragma unroll
            for (int i = 0; i < 4; i++)
                a[i] = *(const short8*)&H1[i * 16 + ln15][k0 + kc + quad * 8];
#pragma unroll
            for (int j = 0; j < 2; j++)
                b[j] = *(const short8*)&Wt[wv * 32 + j * 16 + ln15][kc + quad * 8];
#pragma unroll
            for (int i = 0; i < 4; i++)
#pragma unroll
                for (int j = 0; j < 2; j++)
                    acc2[i][j] = __builtin_amdgcn_mfma_f32_16x16x32_bf16(
                        a[i], b[j], acc2[i][j], 0, 0, 0);
        }
        __syncthreads();
    }
    {
        float bb2[2];
#pragma unroll
        for (int j = 0; j < 2; j++) bb2[j] = b2[wv * 32 + j * 16 + ln15];
#pragma unroll
        for (int i = 0; i < 4; i++)
#pragma unroll
        for (int r = 0; r < 4; r++) {
            const size_t p = p0 + i * 16 + quad * 4 + r;
#pragma unroll
            for (int j = 0; j < 2; j++) {
                const int ch = wv * 32 + j * 16 + ln15;
                const size_t idx = p * 128 + ch;
                f[idx] = f2bf(bfu(f[idx]) + acc2[i][j][r] + bb2[j]);
            }
        }
    }
}

// ---------------------------------------------------------------------------
// MFMA axial decay attention, both directions in one launch (blockIdx.y).
// dir 0: along H -> oh;  dir 1: along W -> ow.  No read-modify-write.
// ---------------------------------------------------------------------------
__global__ __launch_bounds__(256)
void attn_k(const ushort* __restrict__ qkv, ushort* __restrict__ oh,
            ushort* __restrict__ ow)
{
    __shared__ ushort VtS[4][16 * 72];    // V^T [d][j], stride 72
    __shared__ ushort SbS[4][64 * 72];    // S   [i][j], stride 72
    __shared__ float dpow[128];           // dpow[k] = e^{dec*|k-63|}
    const int t = threadIdx.x, wv = t >> 6, lane = t & 63;
    const int ln15 = lane & 15, quad = lane >> 4;
    const int dirH = (blockIdx.y == 0);
    ushort* outb = dirH ? oh : ow;
    const int blk = blockIdx.x;               // (b*8+n)*16 + lg
    const int lg = blk & 15, n = (blk >> 4) & 7, b = blk >> 7;
    if (t < 128) {
        const float dec = logf(1.f - exp2f(-2.f - 0.5f * (float)n));
        int d = t - 63; if (d < 0) d = -d;
        dpow[t] = __expf(dec * (float)d);
    }
    const int fixed = lg * 4 + wv;
    const int stride = dirH ? 64 : 1;
    const size_t base = (size_t)b * 4096 + (dirH ? fixed : fixed * 64);
    const size_t cbase = base * 384 + n * 16;

    // ---- stage V^T into LDS (lane = position j) ----
    {
        const ushort* vp = qkv + cbase + (size_t)lane * stride * 384 + 256;
        const uint4 va = *(const uint4*)vp, vb = *(const uint4*)(vp + 8);
        ushort* vt = VtS[wv] + lane;
        const unsigned int w[8] = { va.x, va.y, va.z, va.w, vb.x, vb.y, vb.z, vb.w };
#pragma unroll
        for (int d = 0; d < 8; d++) {
            vt[(2 * d) * 72]     = (ushort)(w[d] & 0xffff);
            vt[(2 * d + 1) * 72] = (ushort)(w[d] >> 16);
        }
    }
    // ---- load Q/K fragments (16x16x32, K dim padded 16->32) ----
    short8 qa[4], kb[4];
    {
        const short8 z = {0, 0, 0, 0, 0, 0, 0, 0};
#pragma unroll
        for (int mt = 0; mt < 4; mt++) {
            const int i = mt * 16 + ln15;
            if (quad < 2) {
                const ushort* qp = qkv + cbase + (size_t)i * stride * 384 + quad * 8;
                qa[mt] = *(const short8*)qp;
                kb[mt] = *(const short8*)(qp + 128);
            } else { qa[mt] = z; kb[mt] = z; }
        }
    }
    __syncthreads();

    // ---- QK^T + decay -> Sb (bf16 row-major) ----
#pragma unroll
    for (int mt = 0; mt < 4; mt++) {
#pragma unroll
        for (int nt = 0; nt < 4; nt++) {
            floatx4 c = {0.f, 0.f, 0.f, 0.f};
            c = __builtin_amdgcn_mfma_f32_16x16x32_bf16(qa[mt], kb[nt], c, 0, 0, 0);
            const int i0 = mt * 16 + quad * 4;
            const int jl = nt * 16 + ln15;
            const float* lut = dpow + (i0 - jl + 63);
            ushort* sb = SbS[wv] + i0 * 72 + jl;
#pragma unroll
            for (int r = 0; r < 4; r++)
                sb[r * 72] = f2bf(c[r] * lut[r]);
        }
    }
    __syncthreads();

    // ---- O^T = V^T * S^T  (M=16 d, N=64 i, K=64 j) ----
    short8 av[2];
#pragma unroll
    for (int c = 0; c < 2; c++)
        av[c] = *(const short8*)&VtS[wv][ln15 * 72 + c * 32 + quad * 8];
    floatx4 o[4] = {};
#pragma unroll
    for (int nt4 = 0; nt4 < 4; nt4++) {
#pragma unroll
        for (int c = 0; c < 2; c++) {
            const short8 bs = *(const short8*)
                &SbS[wv][(nt4 * 16 + ln15) * 72 + c * 32 + quad * 8];
            o[nt4] = __builtin_amdgcn_mfma_f32_16x16x32_bf16(av[c], bs, o[nt4], 0, 0, 0);
        }
    }
#pragma unroll
    for (int nt4 = 0; nt4 < 4; nt4++) {
        const int i = nt4 * 16 + ln15;
        ushort* op = outb + (base + (size_t)i * stride) * 128 + n * 16 + quad * 4;
        uint2 w;
        w.x = (unsigned int)f2bf(o[nt4][0]) | ((unsigned int)f2bf(o[nt4][1]) << 16);
        w.y = (unsigned int)f2bf(o[nt4][2]) | ((unsigned int)f2bf(o[nt4][3]) << 16);
        *(uint2*)op = w;
    }
}

// ---------------------------------------------------------------------------
extern "C" void kernel_launch(void* const* d_in, const int* in_sizes, int n_in,
                              void* d_out, int out_size, void* d_ws, size_t ws_size,
                              hipStream_t stream)
{
    const float* x      = (const float*)d_in[0];
    const float* cv1_w  = (const float*)d_in[1];
    const float* bn1_g  = (const float*)d_in[2];
    const float* bn1_b  = (const float*)d_in[3];
    const float* bn1_m  = (const float*)d_in[4];
    const float* bn1_v  = (const float*)d_in[5];
    const float* cv2_w  = (const float*)d_in[6];
    const float* bn2_g  = (const float*)d_in[7];
    const float* bn2_b  = (const float*)d_in[8];
    const float* bn2_m  = (const float*)d_in[9];
    const float* bn2_v  = (const float*)d_in[10];
    const float* ln1_g  = (const float*)d_in[11];
    const float* ln1_b  = (const float*)d_in[12];
    const float* qkv_w  = (const float*)d_in[13];
    const float* qkv_b  = (const float*)d_in[14];
    const float* proj_w = (const float*)d_in[15];
    const float* proj_b = (const float*)d_in[16];
    const float* gamma  = (const float*)d_in[17];
    const float* ln2_g  = (const float*)d_in[18];
    const float* ln2_b  = (const float*)d_in[19];
    const float* ffn_w1 = (const float*)d_in[20];
    const float* ffn_b1 = (const float*)d_in[21];
    const float* ffn_w2 = (const float*)d_in[22];
    const float* ffn_b2 = (const float*)d_in[23];

    ushort* W = (ushort*)d_ws;
    ushort* y    = W;                                  // N*256 bf16
    ushort* f    = y    + (size_t)NPOS * 256;          // N*128
    ushort* tmp  = f    + (size_t)NPOS * 128;          // N*128 (fn1 / oh / fn2)
    ushort* owb  = tmp  + (size_t)NPOS * 128;          // N*128 (out_w)
    ushort* qkvb = owb  + (size_t)NPOS * 128;          // N*384
    ushort* xT   = qkvb + (size_t)NPOS * 384;          // N*256
    ushort* wc1  = xT   + (size_t)NPOS * 256;          // 65536
    ushort* wqkv = wc1  + 65536;                       // 49152
    ushort* wpr  = wqkv + 49152;                       // 16384
    ushort* ww1  = wpr  + 16384;                       // 32768
    ushort* ww2  = ww1  + 32768;                       // 32768
    ushort* wc2  = ww2  + 32768;                       // 98304
    float*  bns1 = (float*)(wc2 + 98304);              // 256
    float*  bnb1 = bns1 + 256;
    float*  bns2 = bnb1 + 256;
    float*  bnb2 = bns2 + 256;
    float*  out  = (float*)d_out;

    WcvtArgs wa;
    wa.src[0] = cv1_w;  wa.dst[0] = wc1;  wa.n[0] = 65536;
    wa.src[1] = qkv_w;  wa.dst[1] = wqkv; wa.n[1] = 49152;
    wa.src[2] = proj_w; wa.dst[2] = wpr;  wa.n[2] = 16384;
    wa.src[3] = ffn_w1; wa.dst[3] = ww1;  wa.n[3] = 32768;
    wa.src[4] = ffn_w2; wa.dst[4] = ww2;  wa.n[4] = 32768;
    wa.src[5] = cv2_w;  wa.dst[5] = wc2;  wa.n[5] = 98304;
    wcvt_k<<<dim3(96, 6), 256, 0, stream>>>(wa);
    bnprep_k<<<2, 256, 0, stream>>>(bn1_g, bn1_b, bn1_m, bn1_v,
                                    bn2_g, bn2_b, bn2_m, bn2_v,
                                    bns1, bnb1, bns2, bnb2);
    tr_k<<<4096, 256, 0, stream>>>(x, xT);

    // 1) cv1 + BN + SiLU -> y ; LN1(y2) -> tmp (fused, o-tile 1 only)
    gemm_k<256, 256, 0, 1, 1><<<dim3(512, 2), 256, 0, stream>>>(
        xT, nullptr, wc1, nullptr, bns1, bnb1, nullptr, ln1_g, ln1_b, tmp, y, 256);
    // 2) qkv = fn1 @ qkv_w^T + b -> qkvb
    gemm_k<128, 128, 0, 0, 0><<<dim3(512, 3), 256, 0, stream>>>(
        tmp, nullptr, wqkv, qkv_b, nullptr, nullptr, nullptr, nullptr, nullptr,
        nullptr, qkvb, 384);
    // 3) axial attention (both dirs) -> tmp (out_h), owb (out_w)
    attn_k<<<dim3(2048, 2), 256, 0, stream>>>(qkvb, tmp, owb);
    // 4) f = y2 + (avg(oh,ow) @ proj^T + b)*gamma ; LN2(f) -> tmp (fused)
    gemm_k<128, 128, 3, 4, 1><<<dim3(512, 1), 256, 0, stream>>>(
        tmp, owb, wpr, proj_b, gamma, nullptr, y, ln2_g, ln2_b, tmp, f, 128);
    // 5) f += W2 @ gelu(W1 @ fn2 + b1) + b2  (fused FFN)
    ffn_k<<<1024, 256, 0, stream>>>(tmp, ww1, ffn_b1, ww2, ffn_b2, f);
    // 6) cv2(concat[y,f]) + BN + SiLU -> out NCHW fp32
    gemm_k<384, 0, 2, 2, 0><<<dim3(512, 2), 256, 0, stream>>>(
        y, f, wc2, nullptr, bns2, bnb2, nullptr, nullptr, nullptr, nullptr, out, 0);
}